// Round 1
// baseline (83.290 us; speedup 1.0000x reference)
//
#include <hip/hip_runtime.h>
#include <math.h>

#define HH 512
#define WW 512
#define SEGS 64
#define SAMPLES 32
#define M 2048          // SEGS*SAMPLES path points / edges
#define TPB 256
#define TWIN 18         // sigmoid truncation half-width (error <= e^-18 per edge)

__device__ __forceinline__ float sigmoidf(float z) {
    return 1.0f / (1.0f + __expf(-z));
}

__global__ __launch_bounds__(TPB) void bezier_render_kernel(
    const float* __restrict__ cp,     // 193*2 floats
    const float* __restrict__ color,  // 3 floats
    float* __restrict__ out)          // H*W*4 floats, channel-last
{
    __shared__ float2 pts[M];          // 16 KB
    __shared__ float  smoothv[WW];     // windowed (exact) sigmoid part
    __shared__ float  cbin[WW + 1];    // step-part bins
    __shared__ float  part[TPB];       // scan workspace

    const int t = threadIdx.x;
    const int y = blockIdx.x;
    const float gy = (float)y;

    // ---- 1) sample cubic beziers into LDS (each block recomputes; trivial) ----
    for (int m = t; m < M; m += TPB) {
        int s = m >> 5;          // segment
        int i = m & 31;          // sample index
        float tt = (float)i * (1.0f / 31.0f);
        float mt = 1.0f - tt;
        float w0 = mt * mt * mt;
        float w1 = 3.0f * mt * mt * tt;
        float w2 = 3.0f * mt * tt * tt;
        float w3 = tt * tt * tt;
        const float* q = cp + 6 * s;   // p0=q[0..1], p1=q[2..3], p2=q[4..5], p3=q[6..7]
        float px = w0 * q[0] + w1 * q[2] + w2 * q[4] + w3 * q[6];
        float py = w0 * q[1] + w1 * q[3] + w2 * q[5] + w3 * q[7];
        pts[m] = make_float2(px, py);
    }
    for (int x = t; x < WW; x += TPB) smoothv[x] = 0.0f;
    for (int x = t; x < WW + 1; x += TPB) cbin[x] = 0.0f;
    __syncthreads();

    // ---- 2) per-edge contribution for this row ----
    for (int e = t; e < M; e += TPB) {
        float2 a = pts[e];
        float2 b = pts[(e + 1) & (M - 1)];
        float dy = b.y - a.y;
        if (fabsf(dy) < 1e-6f) continue;                    // reference mask
        float tc = (gy - a.y) / (dy + 1e-8f);               // exact ref formula
        float v = sigmoidf(tc * 20.0f) * sigmoidf((1.0f - tc) * 20.0f);
        if (v < 1e-7f) continue;                            // sum err <= 2048e-7
        float w = (dy > 0.0f) ? v : -v;                     // valid_t * sign(dy)
        float xc = a.x + tc * (b.x - a.x);
        int A = (int)floorf(xc) - TWIN;                     // first windowed pixel
        // step part: every pixel x < A gets full w; bin at clamp(A,0,W)
        int bin = (A > WW) ? WW : A;
        if (bin > 0) atomicAdd(&cbin[bin], w);
        // windowed exact part: x in [A, A+2*TWIN]
        int lo = (A < 0) ? 0 : A;
        int hi = A + 2 * TWIN; if (hi > WW - 1) hi = WW - 1;
        for (int x = lo; x <= hi; ++x) {
            atomicAdd(&smoothv[x], w * sigmoidf(xc - (float)x));
        }
    }
    __syncthreads();

    // ---- 3) suffix scan of cbin[0..512]: wind_const[x] = sum_{j>x} cbin[j] ----
    float e0 = cbin[2 * t];
    float e1 = cbin[2 * t + 1];
    float extra = (t == TPB - 1) ? cbin[WW] : 0.0f;
    part[t] = e0 + e1 + extra;
    __syncthreads();
    for (int off = 1; off < TPB; off <<= 1) {
        float add = (t + off < TPB) ? part[t + off] : 0.0f;
        __syncthreads();
        part[t] += add;
        __syncthreads();
    }
    // part[t] = sum of cbin[j] for j >= 2t (c[512] included)
    float after = (t < TPB - 1) ? part[t + 1] : 0.0f;   // sum j >= 2t+2
    float wc0 = after + e1 + extra;                      // wind_const at x=2t
    float wc1 = after + extra;                           // wind_const at x=2t+1

    // ---- 4) alpha + output ----
    float r = color[0], g = color[1], bl = color[2];
    int x0 = 2 * t;
    float wind0 = wc0 + smoothv[x0];
    float wind1 = wc1 + smoothv[x0 + 1];
    float a0 = sigmoidf(4.0f * wind0);
    float a1 = sigmoidf(4.0f * wind1);
    float4* out4 = (float4*)out;
    out4[y * WW + x0]     = make_float4(r, g, bl, a0);
    out4[y * WW + x0 + 1] = make_float4(r, g, bl, a1);
}

extern "C" void kernel_launch(void* const* d_in, const int* in_sizes, int n_in,
                              void* d_out, int out_size, void* d_ws, size_t ws_size,
                              hipStream_t stream) {
    const float* cp    = (const float*)d_in[0];  // (193,2) float32
    const float* color = (const float*)d_in[1];  // (3,) float32
    float* out = (float*)d_out;                  // (512,512,4) float32
    bezier_render_kernel<<<dim3(HH), dim3(TPB), 0, stream>>>(cp, color, out);
}

// Round 2
// 72.141 us; speedup vs baseline: 1.1545x; 1.1545x over previous
//
#include <hip/hip_runtime.h>
#include <math.h>

#define HH 512
#define WW 512
#define M 2048          // 64 segs * 32 samples = path points / edges
#define TPB 256
#define TWIN 18         // sigmoid truncation half-width (error <= e^-18 per edge)
#define WPIX (2*TWIN+1) // 37 pixels per window
#define EPB (TPB/WPIX)  // 6 edges processed per dense pass

// fast sigmoid: v_exp + v_rcp (1-ulp rcp; error budget has 5x margin)
__device__ __forceinline__ float sigmoidf(float z) {
    return __builtin_amdgcn_rcpf(1.0f + __expf(-z));
}

__global__ __launch_bounds__(TPB) void bezier_render_kernel(
    const float* __restrict__ cp,     // 193*2 floats
    const float* __restrict__ color,  // 3 floats
    float* __restrict__ out)          // H*W*4 floats, channel-last
{
    __shared__ float  cps[386];        // control points staged once
    __shared__ float2 pts[M];          // 16 KB sampled path
    __shared__ float  smoothv[WW];     // windowed (exact) sigmoid part
    __shared__ float  cbin[WW + 1];    // step-part bins
    __shared__ float  part[TPB];       // scan workspace
    __shared__ float  ax[M];           // compacted active-edge x_cross
    __shared__ float  aw[M];           // compacted active-edge weight
    __shared__ int    nact;

    const int t = threadIdx.x;
    const int y = blockIdx.x;
    const float gy = (float)y;

    // ---- 0) stage control points to LDS; init accumulators ----
    if (t < 193) {
        float2 c = ((const float2*)cp)[t];
        cps[2 * t] = c.x; cps[2 * t + 1] = c.y;
    }
    if (t == 0) nact = 0;
    for (int x = t; x < WW; x += TPB) smoothv[x] = 0.0f;
    for (int x = t; x < WW + 1; x += TPB) cbin[x] = 0.0f;
    __syncthreads();

    // ---- 1) sample cubic beziers into LDS ----
    for (int m = t; m < M; m += TPB) {
        int s = m >> 5;          // segment (broadcast across 32 consecutive lanes)
        int i = m & 31;          // sample index
        float tt = (float)i * (1.0f / 31.0f);
        float mt = 1.0f - tt;
        float w0 = mt * mt * mt;
        float w1 = 3.0f * mt * mt * tt;
        float w2 = 3.0f * mt * tt * tt;
        float w3 = tt * tt * tt;
        const float* q = cps + 6 * s;
        float px = w0 * q[0] + w1 * q[2] + w2 * q[4] + w3 * q[6];
        float py = w0 * q[1] + w1 * q[3] + w2 * q[5] + w3 * q[7];
        pts[m] = make_float2(px, py);
    }
    __syncthreads();

    // ---- 2a) edge scan: step-part bins + compact active edges ----
    for (int e = t; e < M; e += TPB) {
        float2 a = pts[e];
        float2 b = pts[(e + 1) & (M - 1)];
        float dy = b.y - a.y;
        if (fabsf(dy) < 1e-6f) continue;                    // reference mask
        float tc = (gy - a.y) * __builtin_amdgcn_rcpf(dy + 1e-8f);
        // valid_t = sigmoid(20t)*sigmoid(20(1-t)) with a single rcp
        float ea = __expf(-20.0f * tc);
        float eb = __expf(-20.0f * (1.0f - tc));
        float v = __builtin_amdgcn_rcpf((1.0f + ea) * (1.0f + eb));
        if (v < 1e-7f) continue;                            // sum err <= 2048e-7
        float w = (dy > 0.0f) ? v : -v;
        float xc = fmaf(tc, b.x - a.x, a.x);
        int A = (int)floorf(xc) - TWIN;                     // first windowed pixel
        int bin = (A > WW) ? WW : A;                        // pixels x<A get full w
        if (bin > 0) atomicAdd(&cbin[bin], w);
        if (A < WW && A + 2 * TWIN >= 0) {                  // window hits the row
            int idx = atomicAdd(&nact, 1);
            ax[idx] = xc; aw[idx] = w;
        }
    }
    __syncthreads();

    // ---- 2b) dense windowed pass: 37 lanes per active edge, 6 edges/pass ----
    {
        int na = nact;
        int el = t / WPIX;               // 0..6 (lanes 222..255 idle)
        int k  = t - el * WPIX;          // 0..36
        if (el < EPB) {
            for (int e = el; e < na; e += EPB) {
                float xc = ax[e];
                float w  = aw[e];
                int x = (int)floorf(xc) - TWIN + k;
                if ((unsigned)x < (unsigned)WW) {
                    atomicAdd(&smoothv[x], w * sigmoidf(xc - (float)x));
                }
            }
        }
    }
    __syncthreads();

    // ---- 3) suffix scan of cbin[0..512]: wind_const[x] = sum_{j>x} cbin[j] ----
    float e0 = cbin[2 * t];
    float e1 = cbin[2 * t + 1];
    float extra = (t == TPB - 1) ? cbin[WW] : 0.0f;
    part[t] = e0 + e1 + extra;
    __syncthreads();
    for (int off = 1; off < TPB; off <<= 1) {
        float add = (t + off < TPB) ? part[t + off] : 0.0f;
        __syncthreads();
        part[t] += add;
        __syncthreads();
    }
    float after = (t < TPB - 1) ? part[t + 1] : 0.0f;   // sum j >= 2t+2
    float wc0 = after + e1 + extra;                      // wind_const at x=2t
    float wc1 = after + extra;                           // wind_const at x=2t+1

    // ---- 4) alpha + output ----
    float r = color[0], g = color[1], bl = color[2];
    int x0 = 2 * t;
    float a0 = sigmoidf(4.0f * (wc0 + smoothv[x0]));
    float a1 = sigmoidf(4.0f * (wc1 + smoothv[x0 + 1]));
    float4* out4 = (float4*)out;
    out4[y * WW + x0]     = make_float4(r, g, bl, a0);
    out4[y * WW + x0 + 1] = make_float4(r, g, bl, a1);
}

extern "C" void kernel_launch(void* const* d_in, const int* in_sizes, int n_in,
                              void* d_out, int out_size, void* d_ws, size_t ws_size,
                              hipStream_t stream) {
    const float* cp    = (const float*)d_in[0];  // (193,2) float32
    const float* color = (const float*)d_in[1];  // (3,) float32
    float* out = (float*)d_out;                  // (512,512,4) float32
    bezier_render_kernel<<<dim3(HH), dim3(TPB), 0, stream>>>(cp, color, out);
}

// Round 3
// 71.042 us; speedup vs baseline: 1.1724x; 1.0155x over previous
//
#include <hip/hip_runtime.h>
#include <math.h>

#define HH 512
#define WW 512
#define M 2048          // 64 segs * 32 samples = path points / edges
#define TPB 256
#define TWIN 18         // sigmoid truncation half-width (error <= e^-18 per edge)
#define WPIX 37         // 2*TWIN+1 pixels per window
#define EPB 6           // 6 edges per dense pass (6*37 = 222 active lanes)

// fast sigmoid: v_exp + v_rcp (1-ulp rcp; error budget has ~5x margin)
__device__ __forceinline__ float sigmoidf(float z) {
    return __builtin_amdgcn_rcpf(1.0f + __expf(-z));
}

__global__ __launch_bounds__(TPB) void bezier_render_kernel(
    const float* __restrict__ cp,     // 193*2 floats
    const float* __restrict__ color,  // 3 floats
    float* __restrict__ out)          // H*W*4 floats, channel-last
{
    __shared__ float2 cps2[194];       // control points as float2
    __shared__ float2 pts[M];          // 16 KB sampled path
    __shared__ float  smoothv[WW];     // windowed (exact) sigmoid part
    __shared__ float  cbin[WW + 1];    // step-part bins
    __shared__ float  wtot[4];         // per-wave scan totals
    __shared__ float2 act[M];          // compacted (x_cross, w)
    __shared__ int    nact;

    const int t    = threadIdx.x;
    const int lane = t & 63;
    const int wv   = t >> 6;
    const int y    = blockIdx.x;
    const float gy = (float)y;

    // ---- 0) stage control points; init accumulators ----
    if (t < 193) cps2[t] = ((const float2*)cp)[t];
    if (t == 0) { nact = 0; cbin[WW] = 0.0f; }
    for (int x = t; x < WW; x += TPB) { smoothv[x] = 0.0f; cbin[x] = 0.0f; }
    __syncthreads();

    // ---- 1) sample cubic beziers into LDS ----
    for (int m = t; m < M; m += TPB) {
        int s = m >> 5;          // segment (broadcast across 32 consecutive lanes)
        int i = m & 31;
        float tt = (float)i * (1.0f / 31.0f);
        float mt = 1.0f - tt;
        float w0 = mt * mt * mt;
        float w1 = 3.0f * mt * mt * tt;
        float w2 = 3.0f * mt * tt * tt;
        float w3 = tt * tt * tt;
        float2 P0 = cps2[3 * s], P1 = cps2[3 * s + 1];
        float2 P2 = cps2[3 * s + 2], P3 = cps2[3 * s + 3];
        pts[m] = make_float2(w0 * P0.x + w1 * P1.x + w2 * P2.x + w3 * P3.x,
                             w0 * P0.y + w1 * P1.y + w2 * P2.y + w3 * P3.y);
    }
    __syncthreads();

    // ---- 2a) edge scan: EARLY REJECT before any transcendental ----
    // valid_t < 1e-7 is implied by tc outside (-0.8059, 1.8059):
    // sigmoid(20*(-0.8059)) = 9.96e-8. NaN tc (dy ~ -1e-8) fails the
    // range compares -> skipped, consistent with the |dy|<1e-6 mask.
    for (int e = t; e < M; e += TPB) {
        float2 a = pts[e];
        float2 b = pts[(e + 1) & (M - 1)];
        float dy = b.y - a.y;
        float tc = (gy - a.y) * __builtin_amdgcn_rcpf(dy + 1e-8f);
        if (!(fabsf(dy) >= 1e-6f) || !(tc > -0.8059f) || !(tc < 1.8059f)) continue;
        float ea = __expf(-20.0f * tc);
        float eb = __expf(-20.0f * (1.0f - tc));
        float v = __builtin_amdgcn_rcpf((1.0f + ea) * (1.0f + eb));
        float w = (dy > 0.0f) ? v : -v;                 // valid_t * sign(dy)
        float xc = fmaf(tc, b.x - a.x, a.x);
        int A = (int)floorf(xc) - TWIN;                 // first windowed pixel
        int bin = (A > WW) ? WW : A;                    // pixels x<A get full w
        if (bin > 0) atomicAdd(&cbin[bin], w);
        if (A < WW && A > -WPIX) {                      // window overlaps the row
            int idx = atomicAdd(&nact, 1);              // wave-aggregated by compiler
            act[idx] = make_float2(xc, w);
        }
    }
    __syncthreads();

    // ---- 2b) dense windowed pass: 37 lanes per active edge, 6 edges/pass ----
    {
        int na = nact;
        int el = t / WPIX;               // 0..6 (lanes 222..255 idle)
        int k  = t - el * WPIX;          // 0..36
        if (el < EPB) {
            for (int e = el; e < na; e += EPB) {
                float2 xw = act[e];
                int x = (int)floorf(xw.x) - TWIN + k;
                if ((unsigned)x < (unsigned)WW) {
                    atomicAdd(&smoothv[x], xw.y * sigmoidf(xw.x - (float)x));
                }
            }
        }
    }
    __syncthreads();

    // ---- 3) suffix scan of cbin: wind_const[x] = sum_{j>x} cbin[j] ----
    // shfl-based in-wave inclusive suffix scan (no barriers), then combine
    // 4 wave totals through LDS with a single barrier.
    float e0 = cbin[2 * t];
    float e1 = cbin[2 * t + 1];
    float p  = e0 + e1;
    float v  = p;
#pragma unroll
    for (int off = 1; off < 64; off <<= 1) {
        float o = __shfl_down(v, off, 64);
        if (lane + off < 64) v += o;
    }
    if (lane == 0) wtot[wv] = v;         // wave total = suffix at its first lane
    __syncthreads();
    float hsum = 0.0f;
    if (wv < 1) hsum += wtot[1];
    if (wv < 2) hsum += wtot[2];
    if (wv < 3) hsum += wtot[3];
    float S    = v - p + hsum;           // sum of p(u) for threads u > t
    float c512 = cbin[WW];
    float wc1  = S + c512;               // wind_const at x=2t+1
    float wc0  = e1 + wc1;               // wind_const at x=2t

    // ---- 4) alpha + output ----
    float r = color[0], g = color[1], bl = color[2];
    int x0 = 2 * t;
    float a0 = sigmoidf(4.0f * (wc0 + smoothv[x0]));
    float a1 = sigmoidf(4.0f * (wc1 + smoothv[x0 + 1]));
    float4* out4 = (float4*)out;
    out4[y * WW + x0]     = make_float4(r, g, bl, a0);
    out4[y * WW + x0 + 1] = make_float4(r, g, bl, a1);
}

extern "C" void kernel_launch(void* const* d_in, const int* in_sizes, int n_in,
                              void* d_out, int out_size, void* d_ws, size_t ws_size,
                              hipStream_t stream) {
    const float* cp    = (const float*)d_in[0];  // (193,2) float32
    const float* color = (const float*)d_in[1];  // (3,) float32
    float* out = (float*)d_out;                  // (512,512,4) float32
    bezier_render_kernel<<<dim3(HH), dim3(TPB), 0, stream>>>(cp, color, out);
}